// Round 14
// baseline (459.298 us; speedup 1.0000x reference)
//
#include <hip/hip_runtime.h>

typedef unsigned short u16;
typedef unsigned int u32;
typedef __bf16 bf16x8 __attribute__((ext_vector_type(8)));
typedef float f32x4 __attribute__((ext_vector_type(4)));

#define DEVI __device__ __forceinline__

#define BB 16
#define NN 577
#define CC 1024
#define HH 16
#define DD 64
#define BN 9232     // B*N rows
#define PIX 576     // 24*24
#define WW 24
#define CHN 256
#define VROW 584    // padded v^T row length (16B-aligned rows)
#define PSZ (9216 * 256)  // one conv1 partial (elements)

DEVI u16 f2b(float f) {
  u32 u = __builtin_bit_cast(u32, f);
  u32 r = 0x7FFFu + ((u >> 16) & 1u);
  return (u16)((u + r) >> 16);
}

DEVI float b2f(u16 h) { return __builtin_bit_cast(float, (u32)h << 16); }

DEVI bf16x8 ldfrag(const u16* p) {
  uint4 u = *(const uint4*)p;
  return __builtin_bit_cast(bf16x8, u);
}

DEVI f32x4 mfma16(bf16x8 a, bf16x8 b, f32x4 c) {
  return __builtin_amdgcn_mfma_f32_16x16x32_bf16(a, b, c, 0, 0, 0);
}

DEVI void gld_lds16(const u16* g, u16* l) {
  __builtin_amdgcn_global_load_lds((const __attribute__((address_space(1))) void*)g,
                                   (__attribute__((address_space(3))) void*)l, 16, 0, 0);
}

DEVI float gelu_tanh(float v) {
  const float x3 = v * v * v;
  const float t = __expf(1.5957691216057308f * (v + 0.044715f * x3));
  const float th = (t - 1.f) / (t + 1.f);
  return 0.5f * v * (1.f + th);
}

// ---------------- prep: weight bf16 conversion + conv-weight permute + zero page ----
__global__ __launch_bounds__(256) void prep_kernel(
    const float* __restrict__ in_w, const float* __restrict__ out_w,
    const float* __restrict__ c1w, const float* __restrict__ c2w,
    u16* __restrict__ wqkv, u16* __restrict__ wout,
    u16* __restrict__ w1t, u16* __restrict__ w2t, u16* __restrict__ zpad) {
  const int i0 = blockIdx.x * 256 + threadIdx.x;
  const int stride = gridDim.x * 256;
  for (int i = i0; i < 3072 * 1024; i += stride) wqkv[i] = f2b(in_w[i]);
  for (int i = i0; i < 1024 * 1024; i += stride) wout[i] = f2b(out_w[i]);
  for (int i = i0; i < 256 * 9216; i += stride) {
    int oc = i / 9216, rem = i - oc * 9216, tap = rem >> 10, c = rem & 1023;
    w1t[i] = f2b(c1w[(size_t)oc * 9216 + c * 9 + tap]);
  }
  for (int i = i0; i < 1024 * 2304; i += stride) {
    int oc = i / 2304, rem = i - oc * 2304, tap = rem >> 8, c = rem & 255;
    w2t[i] = f2b(c2w[(size_t)oc * 2304 + c * 9 + tap]);
  }
  if (i0 < 128) zpad[i0] = 0;
}

// ---------------- LayerNorm (row of 1024): MODE0 f32 in; MODE1 bf16 in + cls out ----
template <int MODE>
__global__ __launch_bounds__(256) void ln_kernel(
    const float* __restrict__ xf, const u16* __restrict__ xh,
    const float* __restrict__ gam, const float* __restrict__ bet,
    u16* __restrict__ yout, float* __restrict__ oextra) {
  __shared__ float sh[8];
  const int row = blockIdx.x;
  const int tid = threadIdx.x;
  float4 v;
  if constexpr (MODE == 0) {
    v = ((const float4*)(xf + (size_t)row * CC))[tid];
  } else {
    ushort4 uv = ((const ushort4*)(xh + (size_t)row * CC))[tid];
    v = make_float4(b2f(uv.x), b2f(uv.y), b2f(uv.z), b2f(uv.w));
  }
  float s = v.x + v.y + v.z + v.w;
  float qq = v.x * v.x + v.y * v.y + v.z * v.z + v.w * v.w;
#pragma unroll
  for (int off = 32; off > 0; off >>= 1) {
    s += __shfl_down(s, off);
    qq += __shfl_down(qq, off);
  }
  if ((tid & 63) == 0) { sh[tid >> 6] = s; sh[4 + (tid >> 6)] = qq; }
  __syncthreads();
  s = sh[0] + sh[1] + sh[2] + sh[3];
  qq = sh[4] + sh[5] + sh[6] + sh[7];
  const float mu = s * (1.f / 1024.f);
  const float rstd = rsqrtf(qq * (1.f / 1024.f) - mu * mu + 1e-5f);
  const float4 g4 = ((const float4*)gam)[tid];
  const float4 b4 = ((const float4*)bet)[tid];
  const float o0 = (v.x - mu) * rstd * g4.x + b4.x;
  const float o1 = (v.y - mu) * rstd * g4.y + b4.y;
  const float o2 = (v.z - mu) * rstd * g4.z + b4.z;
  const float o3 = (v.w - mu) * rstd * g4.w + b4.w;
  ushort4 st = make_ushort4(f2b(o0), f2b(o1), f2b(o2), f2b(o3));
  *(ushort4*)(yout + (size_t)row * CC + tid * 4) = st;
  if constexpr (MODE == 1) {
    if (row % NN == NN - 1) {
      float4 ov = make_float4(v.x + o0, v.y + o1, v.z + o2, v.w + o3);
      ((float4*)(oextra + (size_t)row * CC))[tid] = ov;
    }
  }
}

struct GArgs {
  const u16* A; const u16* Bm; const float* bias; const float* res; const u16* resH;
  float* outF; u16* outH; u16* outQ; u16* outK; u16* outV; const u16* zpad;
  int M, K;
};

// ===== 256-wide MFMA GEMM, 8 waves, BK=64, k-half staging + counted vmcnt(4) =======
// LDS [buf][half][row][32] u16 (128 KB total); stage = 4 gld_lds/thread per half.
// Phases 0-1 consume half0, 2-3 half1; waits are vmcnt(4) at each half boundary
// (next half + next tile's h0 stay in flight) -> no tile-top drain (T4, m218).
// XOR swizzle: chunk ^= (row>>1)&3 on BOTH source and read (8 bank-bases, 2-way=free).
// MODE 0 QKV:  grid 444 (37m x 12n)   MODE 2 CONV1: grid 324 (9tap x 36m)
// MODE 3 CONV2: grid 288 (2piece x 36m x 4n), piece0 taps 0-4 (NST=20), piece1 taps 5-8
template <int MODE>
__global__ __launch_bounds__(512, 1) void gemm8_kernel(GArgs ag) {
  __shared__ u16 SH[65536];  // A: 2buf x 2half x 8192 @0 ; B same @32768
  const int tid = threadIdx.x;
  const int w = tid >> 6, l = tid & 63;
  const int wm = w >> 2, wn = w & 3;
  const int lr = l & 15, lg = l >> 4;
  const int orig = blockIdx.x;
  const int xcd = orig & 7;
  int mt, nt = 0, tapz = 0, piece = 0, NST;
  if constexpr (MODE == 0) {
    const int wg = (xcd < 4 ? xcd * 56 : 224 + (xcd - 4) * 55) + (orig >> 3);
    nt = wg / 37; mt = wg - nt * 37;
    NST = 16;
  } else if constexpr (MODE == 2) {
    const int wg = (xcd < 4 ? xcd * 41 : 164 + (xcd - 4) * 40) + (orig >> 3);
    tapz = wg / 36; mt = wg - tapz * 36;
    NST = 16;
  } else {
    const int wg = xcd * 36 + (orig >> 3);
    piece = wg / 144;
    const int rem = wg - piece * 144;
    mt = rem >> 2; nt = rem & 3;
    NST = piece ? 16 : 20;
  }
  const int m0 = mt * 256, n0 = nt * ((MODE == 2) ? 0 : 256);

  const int srow4 = tid >> 2;   // 0..127: staging row within a 128-row pass
  const int schk4 = tid & 3;    // logical 16B chunk within the 32-u16 half-row

  auto aSrcH = [&](int row, int kt, int kh) -> const u16* {
    const int ch = schk4 ^ ((row >> 1) & 3);
    const int kc = kt * 64 + kh * 32 + ch * 8;
    if constexpr (MODE == 0) {
      int m = m0 + row;
      m = m < ag.M ? m : ag.M - 1;
      return ag.A + (size_t)m * 1024 + kc;
    } else {
      const int m = m0 + row;  // < 9216 exact
      const int b = m / PIX, p = m - b * PIX;
      const int py = p / WW, px = p - py * WW;
      int tap, c0;
      if constexpr (MODE == 2) { tap = tapz; c0 = kc; }
      else { tap = (piece ? 5 : 0) + (kt >> 2); c0 = (kt & 3) * 64 + kh * 32 + ch * 8; }
      const int py2 = py + (tap / 3) - 1, px2 = px + (tap % 3) - 1;
      if ((u32)py2 < (u32)WW && (u32)px2 < (u32)WW) {
        if constexpr (MODE == 2)
          return ag.A + ((size_t)(b * NN + py2 * WW + px2) * CC + c0);
        else
          return ag.A + ((size_t)(b * PIX + py2 * WW + px2) * CHN + c0);
      }
      return ag.zpad + ch * 8;
    }
  };
  auto bSrcH = [&](int row, int kt, int kh) -> const u16* {
    const int ch = schk4 ^ ((row >> 1) & 3);
    const int kc = kt * 64 + kh * 32 + ch * 8;
    if constexpr (MODE == 0)
      return ag.Bm + (size_t)(n0 + row) * 1024 + kc;
    else if constexpr (MODE == 2)
      return ag.Bm + (size_t)row * 9216 + tapz * 1024 + kc;
    else
      return ag.Bm + (size_t)(n0 + row) * 2304 + (piece ? 1280 : 0) + kc;
  };

  // LDS dest is wave-linear: row*32 + chlog*8 == j*4096 + w*512 + l*8 (u16)
  auto stageHalf = [&](int buf, int kt, int kh) {
#pragma unroll
    for (int j = 0; j < 2; ++j)
      gld_lds16(aSrcH(j * 128 + srow4, kt, kh),
                &SH[buf * 16384 + kh * 8192 + j * 4096 + w * 512]);
#pragma unroll
    for (int j = 0; j < 2; ++j)
      gld_lds16(bSrcH(j * 128 + srow4, kt, kh),
                &SH[32768 + buf * 16384 + kh * 8192 + j * 4096 + w * 512]);
  };

  f32x4 acc[8][4] = {};

  stageHalf(0, 0, 0);
  stageHalf(0, 0, 1);

  for (int kt = 0; kt < NST; ++kt) {
    const int bf = kt & 1, nb = bf ^ 1;
    bf16x8 bfr[4];
#pragma unroll
    for (int p = 0; p < 4; ++p) {
      const int kh = p >> 1;          // k-half (0 or 1)
      const int mg = (p & 1) << 2;    // mi group base (0 or 4)
      if (p == 0) {
        asm volatile("s_waitcnt vmcnt(4)" ::: "memory");   // kt.h0 landed
        __builtin_amdgcn_s_barrier();
        if (kt + 1 < NST) stageHalf(nb, kt + 1, 0);
      } else if (p == 2) {
        if (kt + 1 < NST) { asm volatile("s_waitcnt vmcnt(4)" ::: "memory"); }
        else              { asm volatile("s_waitcnt vmcnt(0)" ::: "memory"); }
        __builtin_amdgcn_s_barrier();
        if (kt + 1 < NST) stageHalf(nb, kt + 1, 1);
      }
      const u16* AB = &SH[bf * 16384 + kh * 8192];
      const u16* BBm = &SH[32768 + bf * 16384 + kh * 8192];
      bf16x8 af[4];
#pragma unroll
      for (int i = 0; i < 4; ++i) {
        const int ra = wm * 128 + (mg + i) * 16 + lr;
        af[i] = ldfrag(&AB[ra * 32 + ((lg ^ ((ra >> 1) & 3)) * 8)]);
      }
      if ((p & 1) == 0) {
#pragma unroll
        for (int i = 0; i < 4; ++i) {
          const int rb = wn * 64 + i * 16 + lr;
          bfr[i] = ldfrag(&BBm[rb * 32 + ((lg ^ ((rb >> 1) & 3)) * 8)]);
        }
      }
      __builtin_amdgcn_s_barrier();
      asm volatile("s_waitcnt lgkmcnt(0)" ::: "memory");
      __builtin_amdgcn_s_setprio(1);
#pragma unroll
      for (int mi = 0; mi < 4; ++mi)
#pragma unroll
        for (int ni = 0; ni < 4; ++ni)
          acc[mg + mi][ni] = mfma16(af[mi], bfr[ni], acc[mg + mi][ni]);
      __builtin_amdgcn_s_setprio(0);
      __builtin_amdgcn_s_barrier();
    }
  }

  // ---- epilogue: row = m0 + wm*128 + mi*16 + lg*4 + r ; col = n0 + wn*64 + ni*16 + lr
  if constexpr (MODE == 2) {
    const int tl = (tapz < 5) ? tapz : tapz - 5;
    u16* pb = (tapz < 5) ? ag.outH : ag.outQ;
#pragma unroll
    for (int mi = 0; mi < 8; ++mi) {
#pragma unroll
      for (int r = 0; r < 4; ++r) {
        const int row = m0 + wm * 128 + mi * 16 + (lg << 2) + r;
#pragma unroll
        for (int ni = 0; ni < 4; ++ni) {
          const int col = wn * 64 + ni * 16 + lr;
          pb[(size_t)tl * PSZ + (size_t)row * CHN + col] = f2b(acc[mi][ni][r]);
        }
      }
    }
    return;
  } else if constexpr (MODE == 3) {
    u16* pb = piece ? ag.outQ : ag.outH;
#pragma unroll
    for (int mi = 0; mi < 8; ++mi) {
#pragma unroll
      for (int r = 0; r < 4; ++r) {
        const int row = m0 + wm * 128 + mi * 16 + (lg << 2) + r;
#pragma unroll
        for (int ni = 0; ni < 4; ++ni) {
          const int col = n0 + wn * 64 + ni * 16 + lr;
          pb[(size_t)row * CC + col] = f2b(acc[mi][ni][r]);
        }
      }
    }
    return;
  } else {
    if (n0 >= 2048) {
      // v: per wave two 64x64 LDS transposes, write v^T n-contiguous
      __syncthreads();
      const int hh = (n0 + wn * 64 - 2048) >> 6;
      u16* scr = SH + w * 5120;
#pragma unroll
      for (int qh = 0; qh < 2; ++qh) {
        if (qh) { asm volatile("s_waitcnt lgkmcnt(0)" ::: "memory"); }
        const int G0 = m0 + wm * 128 + qh * 64;
        const int b0q = G0 / NN;
        const bool ok = (G0 + 63 < ag.M) && (b0q == (G0 + 63) / NN);
        if (ok) {
#pragma unroll
          for (int mi = 0; mi < 4; ++mi) {
#pragma unroll
            for (int ni = 0; ni < 4; ++ni) {
              const f32x4 a4 = acc[qh * 4 + mi][ni];
              const float bv = ag.bias[n0 + wn * 64 + ni * 16 + lr];
              ushort4 st;
              st.x = f2b(a4[0] + bv);
              st.y = f2b(a4[1] + bv);
              st.z = f2b(a4[2] + bv);
              st.w = f2b(a4[3] + bv);
              *(ushort4*)(scr + (ni * 16 + lr) * 80 + mi * 16 + lg * 4) = st;
            }
          }
          asm volatile("s_waitcnt lgkmcnt(0)" ::: "memory");
          const int nb2 = G0 - b0q * NN;
          u16* vb = ag.outV + (size_t)((b0q * 16 + hh) * 64) * VROW;
#pragma unroll
          for (int pass = 0; pass < 8; ++pass) {
            const int d_ = pass * 8 + (l >> 3);
            const int nn = (l & 7) * 8;
            uint4 vv = *(const uint4*)(scr + d_ * 80 + nn);
            u16* dst = vb + (size_t)d_ * VROW + nb2 + nn;
            if (!(nb2 & 1)) {
              ((u32*)dst)[0] = vv.x; ((u32*)dst)[1] = vv.y;
              ((u32*)dst)[2] = vv.z; ((u32*)dst)[3] = vv.w;
            } else {
              u16 tmp[8];
              *(uint4*)tmp = vv;
#pragma unroll
              for (int j = 0; j < 8; ++j) dst[j] = tmp[j];
            }
          }
        } else {
#pragma unroll
          for (int mi = 0; mi < 4; ++mi) {
#pragma unroll
            for (int r = 0; r < 4; ++r) {
              const int row = G0 + mi * 16 + lg * 4 + r;
              if (row >= ag.M) continue;
              const int b = row / NN, n = row - b * NN;
#pragma unroll
              for (int ni = 0; ni < 4; ++ni) {
                const int col = n0 + wn * 64 + ni * 16 + lr;
                const int d = col & 63;
                const float v = acc[qh * 4 + mi][ni][r] + ag.bias[col];
                ag.outV[((size_t)((b * 16 + hh) * 64 + d)) * VROW + n] = f2b(v);
              }
            }
          }
        }
      }
      return;
    }
    const bool isQ = n0 < 1024;
#pragma unroll
    for (int mi = 0; mi < 8; ++mi) {
#pragma unroll
      for (int r = 0; r < 4; ++r) {
        const int row = m0 + wm * 128 + mi * 16 + (lg << 2) + r;
        if (row >= ag.M) continue;
        const int b = row / NN, n = row - b * NN;
#pragma unroll
        for (int ni = 0; ni < 4; ++ni) {
          const int col = n0 + wn * 64 + ni * 16 + lr;
          const int hd = col & 1023, h = hd >> 6, d = hd & 63;
          const float v = acc[mi][ni][r] + ag.bias[col];
          if (isQ)
            ag.outQ[((size_t)(b * 16 + h) * NN + n) * DD + d] = f2b(v * 0.18033688011112042f);
          else
            ag.outK[((size_t)(b * 16 + h) * NN + n) * DD + d] = f2b(v);
        }
      }
    }
  }
}

// ---------------- 128x128 MFMA GEMM (proj only), 3-buffer depth-2 pipeline ----------
template <int MODE>
__global__ __launch_bounds__(256) void gemm_kernel(GArgs ag) {
  __shared__ u16 SH[24576];
  const int tid = threadIdx.x;
  const int w = tid >> 6, l = tid & 63;
  const int wr = w >> 1, wc = w & 1;
  const int lr = l & 15, lg = l >> 4;
  const int bid = blockIdx.x;
  const int nt = bid & 7, mt = bid >> 3;
  const int m0 = mt * 128, n0 = nt * 128;
  const int rA = w * 16 + (l >> 2);
  const int cbs = ((l & 3) ^ ((l >> 3) & 3)) * 8;

  auto stage = [&](int buf, int kt) {
    const int k0 = kt * 32;
    u16* Ald = SH + buf * 4096;
    u16* Bld = SH + 12288 + buf * 4096;
#pragma unroll
    for (int c = 0; c < 2; ++c) {
      const int r = c * 64 + rA;
      int m = m0 + r;
      m = m < ag.M ? m : ag.M - 1;
      gld_lds16(ag.A + (size_t)m * ag.K + (k0 + cbs), &Ald[c * 2048 + w * 512]);
      gld_lds16(ag.Bm + (size_t)(n0 + r) * ag.K + (k0 + cbs), &Bld[c * 2048 + w * 512]);
    }
  };

  f32x4 acc[4][4] = {};
  const int nst = ag.K >> 5;

  stage(0, 0);
  stage(1, 1);

  const int swz = (lr >> 1) & 3;
  int b0 = 0, b1 = 1, b2 = 2;
  for (int kt = 0; kt < nst; ++kt) {
    if (kt + 1 < nst) { asm volatile("s_waitcnt vmcnt(4)" ::: "memory"); }
    else              { asm volatile("s_waitcnt vmcnt(0)" ::: "memory"); }
    __builtin_amdgcn_s_barrier();
    if (kt + 2 < nst) stage(b2, kt + 2);
    bf16x8 af[4], bfr[4];
#pragma unroll
    for (int i = 0; i < 4; ++i)
      af[i] = ldfrag(&SH[b0 * 4096 + (wr * 64 + i * 16 + lr) * 32 + ((lg ^ swz) * 8)]);
#pragma unroll
    for (int i = 0; i < 4; ++i)
      bfr[i] = ldfrag(&SH[12288 + b0 * 4096 + (wc * 64 + i * 16 + lr) * 32 + ((lg ^ swz) * 8)]);
    __builtin_amdgcn_s_setprio(1);
#pragma unroll
    for (int mi = 0; mi < 4; ++mi)
#pragma unroll
      for (int ni = 0; ni < 4; ++ni) acc[mi][ni] = mfma16(af[mi], bfr[ni], acc[mi][ni]);
    __builtin_amdgcn_s_setprio(0);
    const int tmp = b0; b0 = b1; b1 = b2; b2 = tmp;
  }

#pragma unroll
  for (int mi = 0; mi < 4; ++mi) {
#pragma unroll
    for (int r = 0; r < 4; ++r) {
      const int row = m0 + wr * 64 + mi * 16 + lg * 4 + r;
      if (row >= ag.M) continue;
#pragma unroll
      for (int ni = 0; ni < 4; ++ni) {
        const int col = n0 + wc * 64 + ni * 16 + lr;
        const size_t idx = (size_t)row * CC + col;
        ag.outH[idx] = f2b(acc[mi][ni][r] + ag.bias[col] + ag.res[idx]);
      }
    }
  }
}

// ---------------- conv1 reduce: f1 = gelu(sum of 9 bf16 partials + bias) -> bf16 ----
__global__ __launch_bounds__(256) void gelu_reduce_kernel(
    const u16* __restrict__ pA, const u16* __restrict__ pB,
    const float* __restrict__ bias, u16* __restrict__ f1) {
  const size_t i4 = ((size_t)blockIdx.x * 256 + threadIdx.x) * 4;
  const int col = (int)(i4 & 255);
  float s0 = 0.f, s1 = 0.f, s2 = 0.f, s3 = 0.f;
#pragma unroll
  for (int t = 0; t < 5; ++t) {
    ushort4 u = *(const ushort4*)(pA + (size_t)t * PSZ + i4);
    s0 += b2f(u.x); s1 += b2f(u.y); s2 += b2f(u.z); s3 += b2f(u.w);
  }
#pragma unroll
  for (int t = 0; t < 4; ++t) {
    ushort4 u = *(const ushort4*)(pB + (size_t)t * PSZ + i4);
    s0 += b2f(u.x); s1 += b2f(u.y); s2 += b2f(u.z); s3 += b2f(u.w);
  }
  const float4 b4 = *(const float4*)(bias + col);
  ushort4 st = make_ushort4(f2b(gelu_tanh(s0 + b4.x)), f2b(gelu_tanh(s1 + b4.y)),
                            f2b(gelu_tanh(s2 + b4.z)), f2b(gelu_tanh(s3 + b4.w)));
  *(ushort4*)(f1 + i4) = st;
}

// ---------------- conv2 combine: out = p0 + p1 + bias + x2h  (row remap) ------------
__global__ __launch_bounds__(256) void conv2_combine_kernel(
    const u16* __restrict__ p0, const u16* __restrict__ p1,
    const float* __restrict__ bias, const u16* __restrict__ x2h,
    float* __restrict__ out) {
  const size_t i4 = ((size_t)blockIdx.x * 256 + threadIdx.x) * 4;  // over 9216*1024
  const int col = (int)(i4 & 1023);
  const int row = (int)(i4 >> 10);
  const int b = row / PIX, p = row - b * PIX;
  const ushort4 a = *(const ushort4*)(p0 + i4);
  const ushort4 c = *(const ushort4*)(p1 + i4);
  const size_t oidx = ((size_t)(b * NN + p) << 10) + col;
  const ushort4 xh = *(const ushort4*)(x2h + oidx);
  const float4 bv = *(const float4*)(bias + col);
  float4 o;
  o.x = b2f(a.x) + b2f(c.x) + bv.x + b2f(xh.x);
  o.y = b2f(a.y) + b2f(c.y) + bv.y + b2f(xh.y);
  o.z = b2f(a.z) + b2f(c.z) + bv.z + b2f(xh.z);
  o.w = b2f(a.w) + b2f(c.w) + bv.w + b2f(xh.w);
  *(float4*)(out + oidx) = o;
}

// ---------------- fused flash attention v3: 8 waves, QBLK=128, LDS-shared K/V -------
__global__ __launch_bounds__(512) void attn_kernel(
    const u16* __restrict__ q, const u16* __restrict__ k,
    const u16* __restrict__ vt, u16* __restrict__ o) {
  __shared__ u16 SH2[24576];
  const int tid = threadIdx.x;
  const int w = tid >> 6, l = tid & 63;
  const int lr = l & 15, lg = l >> 4;
  const int lg4 = lg * 4;
  const int bid = blockIdx.x;
  const int xcd = bid & 7, gg = bid >> 3;
  const int bh = (gg / 5) * 8 + xcd;
  const int qt = gg % 5;
  const int b = bh >> 4, h = bh & 15;

  const u16* qp = q + (size_t)bh * NN * DD;
  const u16* kp = k + (size_t)bh * NN * DD;
  const u16* vp = vt + (size_t)bh * DD * VROW;

  const int qrow = qt * 128 + w * 16 + lr;
  const int qrc = qrow < NN ? qrow : NN - 1;
  const bf16x8 qf0 = ldfrag(qp + (size_t)qrc * DD + lg * 8);
  const bf16x8 qf1 = ldfrag(qp + (size_t)qrc * DD + 32 + lg * 8);

  const int srow = l >> 3;
  const int schk = (l & 7) ^ (srow & 7);
  auto stage = [&](int buf, int kt) {
    const int kb = kt * 64;
    gld_lds16(kp + (size_t)(kb + w * 8 + srow) * DD + schk * 8,
              &SH2[buf * 4096 + w * 512]);
    gld_lds16(vp + (size_t)(w * 8 + srow) * VROW + kb + schk * 8,
              &SH2[8192 + buf * 4096 + w * 512]);
  };

  f32x4 oa[4] = {};
  float mrow = -1e30f;
  float lsum = 0.f;
  u16* pw = &SH2[16384 + w * 1024];
  const int x7 = lr & 7;
  const int x3 = lr & 3;

  stage(0, 0);
  stage(1, 1);

  for (int kt = 0; kt < 10; ++kt) {
    if (kt <= 7) { asm volatile("s_waitcnt vmcnt(2)" ::: "memory"); }
    else         { asm volatile("s_waitcnt vmcnt(0)" ::: "memory"); }
    __builtin_amdgcn_s_barrier();
    const u16* KB = &SH2[(kt & 1) * 4096];
    const u16* VB = &SH2[8192 + (kt & 1) * 4096];
    const int kb = kt * 64;

    f32x4 s[4] = {};
#pragma unroll
    for (int g = 0; g < 4; ++g) {
      const int row = g * 16 + lr;
      const bf16x8 a0 = ldfrag(&KB[row * 64 + ((lg ^ x7) * 8)]);
      const bf16x8 a1 = ldfrag(&KB[row * 64 + (((4 + lg) ^ x7) * 8)]);
      s[g] = mfma16(a0, qf0, s[g]);
      s[g] = mfma16(a1, qf1, s[g]);
    }
    float t[16];
    const bool last = (kt == 9);
#pragma unroll
    for (int g = 0; g < 4; ++g)
#pragma unroll
      for (int r = 0; r < 4; ++r) {
        const int key = kb + g * 16 + lg4 + r;
        t[g * 4 + r] = (!last || key < NN) ? s[g][r] : -3e38f;
      }
    float pmax = t[0];
#pragma unroll
    for (int i = 1; i < 16; ++i) pmax = fmaxf(pmax, t[i]);
    pmax = fmaxf(pmax, __shfl_xor(pmax, 16));
    pmax = fmaxf(pmax, __shfl_xor(pmax, 32));
    if (!__all(pmax <= mrow + 8.f)) {
      const float mn = fmaxf(mrow, pmax);
      const float corr = exp2f(mrow - mn);
      mrow = mn;
      lsum *= corr;
      float bc[4];
#pragma unroll
      for (int r = 0; r < 4; ++r) bc[r] = __shfl(corr, (l & 48) | (lg4 + r));
#pragma unroll
      for (int g = 0; g < 4; ++g)
#pragma unroll
        for (int r = 0; r < 4; ++r) oa[g][r] *= bc[r];
    }
    float ps[16];
    float rsum = 0.f;
#pragma unroll
    for (int i = 0; i < 16; ++i) { ps[i] = exp2f(t[i] - mrow); rsum += ps[i]; }
    rsum += __shfl_xor(rsum, 16);
    rsum += __shfl_xor(rsum, 32);
    lsum += rsum;
#pragma unroll
    for (int g = 0; g < 4; ++g) {
      u32 w0, w1;
      asm("v_cvt_pk_bf16_f32 %0, %1, %2" : "=v"(w0) : "v"(ps[g * 4 + 0]), "v"(ps[g * 4 + 1]));
      asm("v_cvt_pk_bf16_f32 %0, %1, %2" : "=v"(w1) : "v"(ps[g * 4 + 2]), "v"(ps[g * 4 + 3]));
      const int lc = (g & 1) * 2 + (lg >> 1);
      const int off = (g >> 1) * 512 + lr * 32 + ((lc ^ x3) * 8) + (lg & 1) * 4;
      *(uint2*)(&pw[off]) = make_uint2(w0, w1);
    }
    asm volatile("s_waitcnt lgkmcnt(0)" ::: "memory");
    const bf16x8 paf = ldfrag(&pw[lr * 32 + ((lg ^ x3) * 8)]);
    const bf16x8 pbf = ldfrag(&pw[512 + lr * 32 + ((lg ^ x3) * 8)]);
#pragma unroll
    for (int dg = 0; dg < 4; ++dg) {
      const int row = dg * 16 + lr;
      const bf16x8 v0 = ldfrag(&VB[row * 64 + ((lg ^ x7) * 8)]);
      const bf16x8 v1 = ldfrag(&VB[row * 64 + (((4 + lg) ^ x7) * 8)]);
      oa[dg] = mfma16(paf, v0, oa[dg]);
      oa[dg] = mfma16(pbf, v1, oa[dg]);
    }
    asm volatile("s_waitcnt lgkmcnt(0)" ::: "memory");
    __builtin_amdgcn_s_barrier();
    if (kt + 2 <= 9) stage(kt & 1, kt + 2);
  }

  const int nq = qt * 128 + w * 16 + lg4;
  float linv[4];
#pragma unroll
  for (int r = 0; r < 4; ++r) linv[r] = __shfl(lsum, (l & 48) | (lg4 + r));
#pragma unroll
  for (int r = 0; r < 4; ++r) {
    const int n = nq + r;
    if (n >= NN) continue;
    const float inv = 1.0f / linv[r];
#pragma unroll
    for (int g = 0; g < 4; ++g)
      o[(size_t)(b * NN + n) * CC + h * DD + g * 16 + lr] = f2b(oa[g][r] * inv);
  }
}

// =====================================================================================
extern "C" void kernel_launch(void* const* d_in, const int* in_sizes, int n_in,
                              void* d_out, int out_size, void* d_ws, size_t ws_size,
                              hipStream_t stream) {
  const float* x     = (const float*)d_in[0];
  const float* ln1_g = (const float*)d_in[1];
  const float* ln1_b = (const float*)d_in[2];
  const float* in_w  = (const float*)d_in[3];
  const float* in_b  = (const float*)d_in[4];
  const float* out_w = (const float*)d_in[5];
  const float* out_b = (const float*)d_in[6];
  const float* ln2_g = (const float*)d_in[7];
  const float* ln2_b = (const float*)d_in[8];
  const float* c1w   = (const float*)d_in[9];
  const float* c1b   = (const float*)d_in[10];
  const float* c2w   = (const float*)d_in[11];
  const float* c2b   = (const float*)d_in[12];
  float* out = (float*)d_out;

  char* ws = (char*)d_ws;
  size_t off = 0;
  auto alloc = [&](size_t bytes) {
    void* p = ws + off;
    off += (bytes + 255) & ~(size_t)255;
    return p;
  };
  u16* hb   = (u16*)alloc((size_t)BN * CC * 2);   // LN1 out; attn out; conv1 pA; conv2 p0
  u16* wqkv = (u16*)alloc((size_t)3072 * 1024 * 2);
  u16* wout = (u16*)alloc((size_t)1024 * 1024 * 2);
  u16* w1t  = (u16*)alloc((size_t)256 * 9216 * 2);
  u16* w2t  = (u16*)alloc((size_t)1024 * 2304 * 2);
  u16* qb   = (u16*)alloc((size_t)256 * NN * DD * 2);   // q; later yb (LN2 out)
  u16* kb   = (u16*)alloc((size_t)256 * NN * DD * 2);   // k; later f1
  u16* vtb  = (u16*)alloc((size_t)256 * DD * VROW * 2 + 16384);  // v^T; conv1 pB; conv2 p1
  u16* x2h  = (u16*)alloc((size_t)BN * CC * 2);
  u16* zpad = (u16*)alloc(256);
  u16* ob = hb;
  u16* yb = qb;
  u16* f1 = kb;
  u16* pA = hb;
  u16* pB = vtb;

  prep_kernel<<<1024, 256, 0, stream>>>(in_w, out_w, c1w, c2w, wqkv, wout, w1t, w2t, zpad);
  ln_kernel<0><<<BN, 256, 0, stream>>>(x, nullptr, ln1_g, ln1_b, hb, nullptr);
  {
    GArgs a{hb, wqkv, in_b, nullptr, nullptr, nullptr, nullptr, qb, kb, vtb, zpad, BN, CC};
    gemm8_kernel<0><<<444, 512, 0, stream>>>(a);
  }
  attn_kernel<<<1280, 512, 0, stream>>>(qb, kb, vtb, ob);
  {
    GArgs a{ob, wout, out_b, x, nullptr, nullptr, x2h, nullptr, nullptr, nullptr, zpad, BN, CC};
    gemm_kernel<1><<<584, 256, 0, stream>>>(a);
  }
  ln_kernel<1><<<BN, 256, 0, stream>>>(nullptr, x2h, ln2_g, ln2_b, yb, out);
  {
    // conv1: per-tap partials (9tap x 36m = 324 blocks)
    GArgs a{yb, w1t, c1b, nullptr, nullptr, nullptr, pA, pB, nullptr, nullptr, zpad, 9216, 9216};
    gemm8_kernel<2><<<324, 512, 0, stream>>>(a);
  }
  gelu_reduce_kernel<<<2304, 256, 0, stream>>>(pA, pB, c1b, f1);
  {
    // conv2: split-K partials (2piece x 36m x 4n = 288 blocks); p0=hb, p1=vtb
    GArgs a{f1, w2t, c2b, nullptr, nullptr, nullptr, hb, vtb, nullptr, nullptr, zpad, 9216, 2304};
    gemm8_kernel<3><<<288, 512, 0, stream>>>(a);
  }
  conv2_combine_kernel<<<9216, 256, 0, stream>>>(hb, vtb, c2b, x2h, out);
}

// Round 15
// 380.059 us; speedup vs baseline: 1.2085x; 1.2085x over previous
//
#include <hip/hip_runtime.h>

typedef unsigned short u16;
typedef unsigned int u32;
typedef __bf16 bf16x8 __attribute__((ext_vector_type(8)));
typedef float f32x4 __attribute__((ext_vector_type(4)));

#define DEVI __device__ __forceinline__

#define BB 16
#define NN 577
#define CC 1024
#define HH 16
#define DD 64
#define BN 9232     // B*N rows
#define PIX 576     // 24*24
#define WW 24
#define CHN 256
#define VROW 584    // padded v^T row length (16B-aligned rows)
#define PSZ (9216 * 256)  // one conv1 partial (elements)

DEVI u16 f2b(float f) {
  u32 u = __builtin_bit_cast(u32, f);
  u32 r = 0x7FFFu + ((u >> 16) & 1u);
  return (u16)((u + r) >> 16);
}

DEVI float b2f(u16 h) { return __builtin_bit_cast(float, (u32)h << 16); }

DEVI bf16x8 ldfrag(const u16* p) {
  uint4 u = *(const uint4*)p;
  return __builtin_bit_cast(bf16x8, u);
}

DEVI f32x4 mfma16(bf16x8 a, bf16x8 b, f32x4 c) {
  return __builtin_amdgcn_mfma_f32_16x16x32_bf16(a, b, c, 0, 0, 0);
}

DEVI void gld_lds16(const u16* g, u16* l) {
  __builtin_amdgcn_global_load_lds((const __attribute__((address_space(1))) void*)g,
                                   (__attribute__((address_space(3))) void*)l, 16, 0, 0);
}

DEVI float gelu_tanh(float v) {
  const float x3 = v * v * v;
  const float t = __expf(1.5957691216057308f * (v + 0.044715f * x3));
  const float th = (t - 1.f) / (t + 1.f);
  return 0.5f * v * (1.f + th);
}

// ---------------- prep: weight bf16 conversion + conv-weight permute + zero page ----
__global__ __launch_bounds__(256) void prep_kernel(
    const float* __restrict__ in_w, const float* __restrict__ out_w,
    const float* __restrict__ c1w, const float* __restrict__ c2w,
    u16* __restrict__ wqkv, u16* __restrict__ wout,
    u16* __restrict__ w1t, u16* __restrict__ w2t, u16* __restrict__ zpad) {
  const int i0 = blockIdx.x * 256 + threadIdx.x;
  const int stride = gridDim.x * 256;
  for (int i = i0; i < 3072 * 1024; i += stride) wqkv[i] = f2b(in_w[i]);
  for (int i = i0; i < 1024 * 1024; i += stride) wout[i] = f2b(out_w[i]);
  for (int i = i0; i < 256 * 9216; i += stride) {
    int oc = i / 9216, rem = i - oc * 9216, tap = rem >> 10, c = rem & 1023;
    w1t[i] = f2b(c1w[(size_t)oc * 9216 + c * 9 + tap]);
  }
  for (int i = i0; i < 1024 * 2304; i += stride) {
    int oc = i / 2304, rem = i - oc * 2304, tap = rem >> 8, c = rem & 255;
    w2t[i] = f2b(c2w[(size_t)oc * 2304 + c * 9 + tap]);
  }
  if (i0 < 128) zpad[i0] = 0;
}

// ---------------- LayerNorm (row of 1024): MODE0 f32 in; MODE1 bf16 in + cls out ----
template <int MODE>
__global__ __launch_bounds__(256) void ln_kernel(
    const float* __restrict__ xf, const u16* __restrict__ xh,
    const float* __restrict__ gam, const float* __restrict__ bet,
    u16* __restrict__ yout, float* __restrict__ oextra) {
  __shared__ float sh[8];
  const int row = blockIdx.x;
  const int tid = threadIdx.x;
  float4 v;
  if constexpr (MODE == 0) {
    v = ((const float4*)(xf + (size_t)row * CC))[tid];
  } else {
    ushort4 uv = ((const ushort4*)(xh + (size_t)row * CC))[tid];
    v = make_float4(b2f(uv.x), b2f(uv.y), b2f(uv.z), b2f(uv.w));
  }
  float s = v.x + v.y + v.z + v.w;
  float qq = v.x * v.x + v.y * v.y + v.z * v.z + v.w * v.w;
#pragma unroll
  for (int off = 32; off > 0; off >>= 1) {
    s += __shfl_down(s, off);
    qq += __shfl_down(qq, off);
  }
  if ((tid & 63) == 0) { sh[tid >> 6] = s; sh[4 + (tid >> 6)] = qq; }
  __syncthreads();
  s = sh[0] + sh[1] + sh[2] + sh[3];
  qq = sh[4] + sh[5] + sh[6] + sh[7];
  const float mu = s * (1.f / 1024.f);
  const float rstd = rsqrtf(qq * (1.f / 1024.f) - mu * mu + 1e-5f);
  const float4 g4 = ((const float4*)gam)[tid];
  const float4 b4 = ((const float4*)bet)[tid];
  const float o0 = (v.x - mu) * rstd * g4.x + b4.x;
  const float o1 = (v.y - mu) * rstd * g4.y + b4.y;
  const float o2 = (v.z - mu) * rstd * g4.z + b4.z;
  const float o3 = (v.w - mu) * rstd * g4.w + b4.w;
  ushort4 st = make_ushort4(f2b(o0), f2b(o1), f2b(o2), f2b(o3));
  *(ushort4*)(yout + (size_t)row * CC + tid * 4) = st;
  if constexpr (MODE == 1) {
    if (row % NN == NN - 1) {  // cls token row: out = x2 + ln2(x2)
      float4 ov = make_float4(v.x + o0, v.y + o1, v.z + o2, v.w + o3);
      ((float4*)(oextra + (size_t)row * CC))[tid] = ov;
    }
  }
}

struct GArgs {
  const u16* A; const u16* Bm; const float* bias; const float* res; const u16* resH;
  float* outF; u16* outH; u16* outQ; u16* outK; u16* outV; const u16* zpad;
  int M, K;
};

// ================= QKV: 256x256 8-phase-style MFMA GEMM (m201 template) ==============
// 512 thr, 8 waves (2M x 4N, wave tile 128x64), BK=64, 128 KB dbuf LDS.
// Per K-tile: 4 phases of {ds_read subtile + 2 staging gld_lds -> barrier ->
// lgkmcnt(0) -> setprio(1) 16 MFMA setprio(0) -> barrier}; vmcnt(0)+barrier per tile.
__global__ __launch_bounds__(512, 1) void qkv_kernel(GArgs ag) {
  __shared__ u16 SH[65536];  // A: 2 x 16384 @0 ; B: 2 x 16384 @32768  (128 KB)
  const int tid = threadIdx.x;
  const int w = tid >> 6, l = tid & 63;
  const int wm = w >> 2, wn = w & 3;
  const int lr = l & 15, lg = l >> 4;
  // grid 444 = 37m x 12n; bijective XCD chunk (m204): q=55, r=4
  const int orig = blockIdx.x;
  const int xcd = orig & 7;
  const int wg = (xcd < 4 ? xcd * 56 : 224 + (xcd - 4) * 55) + (orig >> 3);
  const int nt = wg / 37, mt = wg - nt * 37;
  const int m0 = mt * 256, n0 = nt * 256;

  const int srow = tid >> 3;           // staging row within a 64-row pass
  const int schk = tid & 7;

  auto stageA = [&](int buf, int kt, int j) {
    const int row = j * 64 + srow;
    const int ch = schk ^ (row & 7);
    int m = m0 + row;
    m = m < ag.M ? m : ag.M - 1;
    gld_lds16(ag.A + (size_t)m * 1024 + kt * 64 + ch * 8,
              &SH[buf * 16384 + (j * 64 + w * 8) * 64]);
  };
  auto stageB = [&](int buf, int kt, int j) {
    const int row = j * 64 + srow;
    const int ch = schk ^ (row & 7);
    gld_lds16(ag.Bm + (size_t)(n0 + row) * 1024 + kt * 64 + ch * 8,
              &SH[32768 + buf * 16384 + (j * 64 + w * 8) * 64]);
  };

  f32x4 acc[8][4] = {};

#pragma unroll
  for (int j = 0; j < 4; ++j) { stageA(0, 0, j); stageB(0, 0, j); }

  for (int kt = 0; kt < 16; ++kt) {
    asm volatile("s_waitcnt vmcnt(0)" ::: "memory");
    __builtin_amdgcn_s_barrier();
    const int bf = kt & 1, nb = bf ^ 1;
    const u16* AB = &SH[bf * 16384];
    const u16* BBm = &SH[32768 + bf * 16384];
    bf16x8 bfr[4];
#pragma unroll
    for (int ph = 0; ph < 4; ++ph) {
      const int mg = (ph & 1) << 2;   // mi group base (0 or 4)
      const int kh = ph >> 1;         // k-half (0 or 1)
      bf16x8 af[4];
#pragma unroll
      for (int i = 0; i < 4; ++i) {
        const int ra = wm * 128 + (mg + i) * 16 + lr;
        af[i] = ldfrag(&AB[ra * 64 + (((kh << 2) + lg) ^ (ra & 7)) * 8]);
      }
      if ((ph & 1) == 0) {
#pragma unroll
        for (int i = 0; i < 4; ++i) {
          const int rb = wn * 64 + i * 16 + lr;
          bfr[i] = ldfrag(&BBm[rb * 64 + (((kh << 2) + lg) ^ (rb & 7)) * 8]);
        }
      }
      if (kt + 1 < 16) {
        stageA(nb, kt + 1, ph);
        stageB(nb, kt + 1, ph);
      }
      __builtin_amdgcn_s_barrier();
      asm volatile("s_waitcnt lgkmcnt(0)" ::: "memory");
      __builtin_amdgcn_s_setprio(1);
#pragma unroll
      for (int mi = 0; mi < 4; ++mi)
#pragma unroll
        for (int ni = 0; ni < 4; ++ni)
          acc[mg + mi][ni] = mfma16(af[mi], bfr[ni], acc[mg + mi][ni]);
      __builtin_amdgcn_s_setprio(0);
      __builtin_amdgcn_s_barrier();
    }
  }

  // ---- epilogue: row = m0 + wm*128 + mi*16 + lg*4 + r ; col = n0 + wn*64 + ni*16 + lr
  if (n0 >= 2048) {
    // v: per wave two 64x64 LDS transposes, write v^T n-contiguous
    __syncthreads();
    const int hh = (n0 + wn * 64 - 2048) >> 6;
    u16* scr = SH + w * 5120;  // 64 x 80 u16 per wave (8 waves = 80 KB)
#pragma unroll
    for (int qh = 0; qh < 2; ++qh) {
      if (qh) { asm volatile("s_waitcnt lgkmcnt(0)" ::: "memory"); }
      const int G0 = m0 + wm * 128 + qh * 64;
      const int b0q = G0 / NN;
      const bool ok = (G0 + 63 < ag.M) && (b0q == (G0 + 63) / NN);
      if (ok) {
#pragma unroll
        for (int mi = 0; mi < 4; ++mi) {
#pragma unroll
          for (int ni = 0; ni < 4; ++ni) {
            const f32x4 a4 = acc[qh * 4 + mi][ni];
            const float bv = ag.bias[n0 + wn * 64 + ni * 16 + lr];
            ushort4 st;
            st.x = f2b(a4[0] + bv);
            st.y = f2b(a4[1] + bv);
            st.z = f2b(a4[2] + bv);
            st.w = f2b(a4[3] + bv);
            *(ushort4*)(scr + (ni * 16 + lr) * 80 + mi * 16 + lg * 4) = st;
          }
        }
        asm volatile("s_waitcnt lgkmcnt(0)" ::: "memory");
        const int nb2 = G0 - b0q * NN;
        u16* vb = ag.outV + (size_t)((b0q * 16 + hh) * 64) * VROW;
#pragma unroll
        for (int pass = 0; pass < 8; ++pass) {
          const int d_ = pass * 8 + (l >> 3);
          const int nn = (l & 7) * 8;
          uint4 vv = *(const uint4*)(scr + d_ * 80 + nn);
          u16* dst = vb + (size_t)d_ * VROW + nb2 + nn;
          if (!(nb2 & 1)) {
            ((u32*)dst)[0] = vv.x; ((u32*)dst)[1] = vv.y;
            ((u32*)dst)[2] = vv.z; ((u32*)dst)[3] = vv.w;
          } else {
            u16 tmp[8];
            *(uint4*)tmp = vv;
#pragma unroll
            for (int j = 0; j < 8; ++j) dst[j] = tmp[j];
          }
        }
      } else {
#pragma unroll
        for (int mi = 0; mi < 4; ++mi) {
#pragma unroll
          for (int r = 0; r < 4; ++r) {
            const int row = G0 + mi * 16 + lg * 4 + r;
            if (row >= ag.M) continue;
            const int b = row / NN, n = row - b * NN;
#pragma unroll
            for (int ni = 0; ni < 4; ++ni) {
              const int col = n0 + wn * 64 + ni * 16 + lr;
              const int d = col & 63;
              const float v = acc[qh * 4 + mi][ni][r] + ag.bias[col];
              ag.outV[((size_t)((b * 16 + hh) * 64 + d)) * VROW + n] = f2b(v);
            }
          }
        }
      }
    }
    return;
  }
  const bool isQ = n0 < 1024;
#pragma unroll
  for (int mi = 0; mi < 8; ++mi) {
#pragma unroll
    for (int r = 0; r < 4; ++r) {
      const int row = m0 + wm * 128 + mi * 16 + (lg << 2) + r;
      if (row >= ag.M) continue;
      const int b = row / NN, n = row - b * NN;
#pragma unroll
      for (int ni = 0; ni < 4; ++ni) {
        const int col = n0 + wn * 64 + ni * 16 + lr;
        const int hd = col & 1023, h = hd >> 6, d = hd & 63;
        const float v = acc[mi][ni][r] + ag.bias[col];
        if (isQ)
          ag.outQ[((size_t)(b * 16 + h) * NN + n) * DD + d] = f2b(v * 0.18033688011112042f);
        else
          ag.outK[((size_t)(b * 16 + h) * NN + n) * DD + d] = f2b(v);
      }
    }
  }
}

// ---------------- 128x128 MFMA GEMM, BK=32, 3-buffer depth-2 pipeline (48 KB LDS) ---
// 1-D grids, XCD-chunked: MODE1 584=8x73, MODE3 576=8x72, MODE4 1296=8x162 tap-major
template <int MODE>
__global__ __launch_bounds__(256) void gemm_kernel(GArgs ag) {
  __shared__ u16 SH[24576];
  const int tid = threadIdx.x;
  const int w = tid >> 6, l = tid & 63;
  const int wr = w >> 1, wc = w & 1;
  const int lr = l & 15, lg = l >> 4;
  const int bid = blockIdx.x;
  int mt, nt, tapz = 0;
  if constexpr (MODE == 1 || MODE == 3) {
    nt = bid & 7; mt = bid >> 3;
  } else {
    const int g = (bid & 7) * 162 + (bid >> 3);
    tapz = g / 144;
    const int rem = g - tapz * 144;
    nt = rem / 72; mt = rem - nt * 72;
  }
  const int m0 = mt * 128, n0 = nt * 128;
  const int rA = w * 16 + (l >> 2);
  const int cbs = ((l & 3) ^ ((l >> 3) & 3)) * 8;

  auto stage = [&](int buf, int kt) {
    const int k0 = kt * 32;
    u16* Ald = SH + buf * 4096;
    u16* Bld = SH + 12288 + buf * 4096;
#pragma unroll
    for (int c = 0; c < 2; ++c) {
      const int r = c * 64 + rA;
      const u16* asrc;
      if constexpr (MODE == 1) {
        int m = m0 + r;
        m = m < ag.M ? m : ag.M - 1;
        asrc = ag.A + (size_t)m * ag.K + (k0 + cbs);
      } else {
        const int m = m0 + r;
        const int b = m / PIX, p = m - b * PIX;
        const int py = p / WW, px = p - py * WW;
        constexpr int CKc = (MODE == 3) ? 256 : 1024;
        const int tap = (MODE == 4) ? tapz : (k0 / CKc);
        const int c0 = (MODE == 4) ? k0 : (k0 - tap * CKc);
        const int py2 = py + (tap / 3) - 1, px2 = px + (tap % 3) - 1;
        if ((u32)py2 < (u32)WW && (u32)px2 < (u32)WW) {
          if constexpr (MODE == 4)
            asrc = ag.A + ((size_t)(b * NN + py2 * WW + px2) * CC + c0 + cbs);
          else
            asrc = ag.A + ((size_t)(b * PIX + py2 * WW + px2) * CHN + c0 + cbs);
        } else {
          asrc = ag.zpad + cbs;
        }
      }
      gld_lds16(asrc, &Ald[c * 2048 + w * 512]);
      const u16* bsrc;
      if constexpr (MODE == 4)
        bsrc = ag.Bm + (size_t)(n0 + r) * 9216 + (tapz * 1024 + k0 + cbs);
      else
        bsrc = ag.Bm + (size_t)(n0 + r) * ag.K + (k0 + cbs);
      gld_lds16(bsrc, &Bld[c * 2048 + w * 512]);
    }
  };

  f32x4 acc[4][4] = {};
  const int KL = (MODE == 4) ? 1024 : ag.K;
  const int nst = KL >> 5;

  stage(0, 0);
  stage(1, 1);

  const int swz = (lr >> 1) & 3;
  int b0 = 0, b1 = 1, b2 = 2;
  for (int kt = 0; kt < nst; ++kt) {
    if (kt + 1 < nst) { asm volatile("s_waitcnt vmcnt(4)" ::: "memory"); }
    else              { asm volatile("s_waitcnt vmcnt(0)" ::: "memory"); }
    __builtin_amdgcn_s_barrier();
    if (kt + 2 < nst) stage(b2, kt + 2);
    bf16x8 af[4], bfr[4];
#pragma unroll
    for (int i = 0; i < 4; ++i)
      af[i] = ldfrag(&SH[b0 * 4096 + (wr * 64 + i * 16 + lr) * 32 + ((lg ^ swz) * 8)]);
#pragma unroll
    for (int i = 0; i < 4; ++i)
      bfr[i] = ldfrag(&SH[12288 + b0 * 4096 + (wc * 64 + i * 16 + lr) * 32 + ((lg ^ swz) * 8)]);
    __builtin_amdgcn_s_setprio(1);
#pragma unroll
    for (int mi = 0; mi < 4; ++mi)
#pragma unroll
      for (int ni = 0; ni < 4; ++ni) acc[mi][ni] = mfma16(af[mi], bfr[ni], acc[mi][ni]);
    __builtin_amdgcn_s_setprio(0);
    const int tmp = b0; b0 = b1; b1 = b2; b2 = tmp;
  }

#pragma unroll
  for (int mi = 0; mi < 4; ++mi) {
#pragma unroll
    for (int r = 0; r < 4; ++r) {
      const int row = m0 + wr * 64 + mi * 16 + lg * 4 + r;
      if (row >= ag.M) continue;
#pragma unroll
      for (int ni = 0; ni < 4; ++ni) {
        const int col = n0 + wc * 64 + ni * 16 + lr;
        if constexpr (MODE == 4) {
          u16* pb = (tapz < 5) ? ag.outH : ag.outQ;
          const int tl = (tapz < 5) ? tapz : tapz - 5;
          pb[(size_t)tl * PSZ + (size_t)row * CHN + col] = f2b(acc[mi][ni][r]);
        } else if constexpr (MODE == 1) {
          const size_t idx = (size_t)row * CC + col;
          ag.outH[idx] = f2b(acc[mi][ni][r] + ag.bias[col] + ag.res[idx]);
        } else {
          const int b = row / PIX, p = row - b * PIX;
          const size_t idx = (size_t)(b * NN + p) * CC + col;
          ag.outF[idx] = acc[mi][ni][r] + ag.bias[col] + b2f(ag.resH[idx]);
        }
      }
    }
  }
}

// ---------------- conv1 reduce: f1 = gelu(sum of 9 bf16 partials + bias) -> bf16 ----
__global__ __launch_bounds__(256) void gelu_reduce_kernel(
    const u16* __restrict__ pA, const u16* __restrict__ pB,
    const float* __restrict__ bias, u16* __restrict__ f1) {
  const size_t i4 = ((size_t)blockIdx.x * 256 + threadIdx.x) * 4;
  const int col = (int)(i4 & 255);
  float s0 = 0.f, s1 = 0.f, s2 = 0.f, s3 = 0.f;
#pragma unroll
  for (int t = 0; t < 5; ++t) {
    ushort4 u = *(const ushort4*)(pA + (size_t)t * PSZ + i4);
    s0 += b2f(u.x); s1 += b2f(u.y); s2 += b2f(u.z); s3 += b2f(u.w);
  }
#pragma unroll
  for (int t = 0; t < 4; ++t) {
    ushort4 u = *(const ushort4*)(pB + (size_t)t * PSZ + i4);
    s0 += b2f(u.x); s1 += b2f(u.y); s2 += b2f(u.z); s3 += b2f(u.w);
  }
  const float4 b4 = *(const float4*)(bias + col);
  ushort4 st = make_ushort4(f2b(gelu_tanh(s0 + b4.x)), f2b(gelu_tanh(s1 + b4.y)),
                            f2b(gelu_tanh(s2 + b4.z)), f2b(gelu_tanh(s3 + b4.w)));
  *(ushort4*)(f1 + i4) = st;
}

// ---------------- fused flash attention v3: 8 waves, QBLK=128, LDS-shared K/V -------
__global__ __launch_bounds__(512) void attn_kernel(
    const u16* __restrict__ q, const u16* __restrict__ k,
    const u16* __restrict__ vt, u16* __restrict__ o) {
  __shared__ u16 SH2[24576];
  const int tid = threadIdx.x;
  const int w = tid >> 6, l = tid & 63;
  const int lr = l & 15, lg = l >> 4;
  const int lg4 = lg * 4;
  const int bid = blockIdx.x;
  const int xcd = bid & 7, gg = bid >> 3;
  const int bh = (gg / 5) * 8 + xcd;
  const int qt = gg % 5;
  const int b = bh >> 4, h = bh & 15;

  const u16* qp = q + (size_t)bh * NN * DD;
  const u16* kp = k + (size_t)bh * NN * DD;
  const u16* vp = vt + (size_t)bh * DD * VROW;

  const int qrow = qt * 128 + w * 16 + lr;
  const int qrc = qrow < NN ? qrow : NN - 1;
  const bf16x8 qf0 = ldfrag(qp + (size_t)qrc * DD + lg * 8);
  const bf16x8 qf1 = ldfrag(qp + (size_t)qrc * DD + 32 + lg * 8);

  const int srow = l >> 3;
  const int schk = (l & 7) ^ (srow & 7);
  auto stage = [&](int buf, int kt) {
    const int kb = kt * 64;
    gld_lds16(kp + (size_t)(kb + w * 8 + srow) * DD + schk * 8,
              &SH2[buf * 4096 + w * 512]);
    gld_lds16(vp + (size_t)(w * 8 + srow) * VROW + kb + schk * 8,
              &SH2[8192 + buf * 4096 + w * 512]);
  };

  f32x4 oa[4] = {};
  float mrow = -1e30f;
  float lsum = 0.f;
  u16* pw = &SH2[16384 + w * 1024];
  const int x7 = lr & 7;
  const int x3 = lr & 3;

  stage(0, 0);
  stage(1, 1);

  for (int kt = 0; kt < 10; ++kt) {
    if (kt <= 7) { asm volatile("s_waitcnt vmcnt(2)" ::: "memory"); }
    else         { asm volatile("s_waitcnt vmcnt(0)" ::: "memory"); }
    __builtin_amdgcn_s_barrier();
    const u16* KB = &SH2[(kt & 1) * 4096];
    const u16* VB = &SH2[8192 + (kt & 1) * 4096];
    const int kb = kt * 64;

    f32x4 s[4] = {};
#pragma unroll
    for (int g = 0; g < 4; ++g) {
      const int row = g * 16 + lr;
      const bf16x8 a0 = ldfrag(&KB[row * 64 + ((lg ^ x7) * 8)]);
      const bf16x8 a1 = ldfrag(&KB[row * 64 + (((4 + lg) ^ x7) * 8)]);
      s[g] = mfma16(a0, qf0, s[g]);
      s[g] = mfma16(a1, qf1, s[g]);
    }
    float t[16];
    const bool last = (kt == 9);
#pragma unroll
    for (int g = 0; g < 4; ++g)
#pragma unroll
      for (int r = 0; r < 4; ++r) {
        const int key = kb + g * 16 + lg4 + r;
        t[g * 4 + r] = (!last || key < NN) ? s[g][r] : -3e38f;
      }
    float pmax = t[0];
#pragma unroll
    for (int i = 1; i < 16; ++i) pmax = fmaxf(pmax, t[i]);
    pmax = fmaxf(pmax, __shfl_xor(pmax, 16));
    pmax = fmaxf(pmax, __shfl_xor(pmax, 32));
    if (!__all(pmax <= mrow + 8.f)) {
      const float mn = fmaxf(mrow, pmax);
      const float corr = exp2f(mrow - mn);
      mrow = mn;
      lsum *= corr;
      float bc[4];
#pragma unroll
      for (int r = 0; r < 4; ++r) bc[r] = __shfl(corr, (l & 48) | (lg4 + r));
#pragma unroll
      for (int g = 0; g < 4; ++g)
#pragma unroll
        for (int r = 0; r < 4; ++r) oa[g][r] *= bc[r];
    }
    float ps[16];
    float rsum = 0.f;
#pragma unroll
    for (int i = 0; i < 16; ++i) { ps[i] = exp2f(t[i] - mrow); rsum += ps[i]; }
    rsum += __shfl_xor(rsum, 16);
    rsum += __shfl_xor(rsum, 32);
    lsum += rsum;
#pragma unroll
    for (int g = 0; g < 4; ++g) {
      u32 w0, w1;
      asm("v_cvt_pk_bf16_f32 %0, %1, %2" : "=v"(w0) : "v"(ps[g * 4 + 0]), "v"(ps[g * 4 + 1]));
      asm("v_cvt_pk_bf16_f32 %0, %1, %2" : "=v"(w1) : "v"(ps[g * 4 + 2]), "v"(ps[g * 4 + 3]));
      const int lc = (g & 1) * 2 + (lg >> 1);
      const int off = (g >> 1) * 512 + lr * 32 + ((lc ^ x3) * 8) + (lg & 1) * 4;
      *(uint2*)(&pw[off]) = make_uint2(w0, w1);
    }
    asm volatile("s_waitcnt lgkmcnt(0)" ::: "memory");
    const bf16x8 paf = ldfrag(&pw[lr * 32 + ((lg ^ x3) * 8)]);
    const bf16x8 pbf = ldfrag(&pw[512 + lr * 32 + ((lg ^ x3) * 8)]);
#pragma unroll
    for (int dg = 0; dg < 4; ++dg) {
      const int row = dg * 16 + lr;
      const bf16x8 v0 = ldfrag(&VB[row * 64 + ((lg ^ x7) * 8)]);
      const bf16x8 v1 = ldfrag(&VB[row * 64 + (((4 + lg) ^ x7) * 8)]);
      oa[dg] = mfma16(paf, v0, oa[dg]);
      oa[dg] = mfma16(pbf, v1, oa[dg]);
    }
    asm volatile("s_waitcnt lgkmcnt(0)" ::: "memory");
    __builtin_amdgcn_s_barrier();
    if (kt + 2 <= 9) stage(kt & 1, kt + 2);
  }

  const int nq = qt * 128 + w * 16 + lg4;
  float linv[4];
#pragma unroll
  for (int r = 0; r < 4; ++r) linv[r] = __shfl(lsum, (l & 48) | (lg4 + r));
#pragma unroll
  for (int r = 0; r < 4; ++r) {
    const int n = nq + r;
    if (n >= NN) continue;
    const float inv = 1.0f / linv[r];
#pragma unroll
    for (int g = 0; g < 4; ++g)
      o[(size_t)(b * NN + n) * CC + h * DD + g * 16 + lr] = f2b(oa[g][r] * inv);
  }
}

// =====================================================================================
extern "C" void kernel_launch(void* const* d_in, const int* in_sizes, int n_in,
                              void* d_out, int out_size, void* d_ws, size_t ws_size,
                              hipStream_t stream) {
  const float* x     = (const float*)d_in[0];
  const float* ln1_g = (const float*)d_in[1];
  const float* ln1_b = (const float*)d_in[2];
  const float* in_w  = (const float*)d_in[3];
  const float* in_b  = (const float*)d_in[4];
  const float* out_w = (const float*)d_in[5];
  const float* out_b = (const float*)d_in[6];
  const float* ln2_g = (const float*)d_in[7];
  const float* ln2_b = (const float*)d_in[8];
  const float* c1w   = (const float*)d_in[9];
  const float* c1b   = (const float*)d_in[10];
  const float* c2w   = (const float*)d_in[11];
  const float* c2b   = (const float*)d_in[12];
  float* out = (float*)d_out;

  char* ws = (char*)d_ws;
  size_t off = 0;
  auto alloc = [&](size_t bytes) {
    void* p = ws + off;
    off += (bytes + 255) & ~(size_t)255;
    return p;
  };
  u16* hb   = (u16*)alloc((size_t)BN * CC * 2);
  u16* wqkv = (u16*)alloc((size_t)3072 * 1024 * 2);
  u16* wout = (u16*)alloc((size_t)1024 * 1024 * 2);
  u16* w1t  = (u16*)alloc((size_t)256 * 9216 * 2);
  u16* w2t  = (u16*)alloc((size_t)1024 * 2304 * 2);
  u16* qb   = (u16*)alloc((size_t)256 * NN * DD * 2);
  u16* kb   = (u16*)alloc((size_t)256 * NN * DD * 2);
  u16* vtb  = (u16*)alloc((size_t)256 * DD * VROW * 2 + 16384);
  u16* x2h  = (u16*)alloc((size_t)BN * CC * 2);
  u16* zpad = (u16*)alloc(256);
  u16* ob = hb;
  u16* yb = qb;
  u16* f1 = kb;
  u16* pA = hb;
  u16* pB = vtb;

  prep_kernel<<<1024, 256, 0, stream>>>(in_w, out_w, c1w, c2w, wqkv, wout, w1t, w2t, zpad);
  ln_kernel<0><<<BN, 256, 0, stream>>>(x, nullptr, ln1_g, ln1_b, hb, nullptr);
  {
    GArgs a{hb, wqkv, in_b, nullptr, nullptr, nullptr, nullptr, qb, kb, vtb, zpad, BN, CC};
    qkv_kernel<<<444, 512, 0, stream>>>(a);
  }
  attn_kernel<<<1280, 512, 0, stream>>>(qb, kb, vtb, ob);
  {
    GArgs a{ob, wout, out_b, x, nullptr, nullptr, x2h, nullptr, nullptr, nullptr, zpad, BN, CC};
    gemm_kernel<1><<<584, 256, 0, stream>>>(a);
  }
  ln_kernel<1><<<BN, 256, 0, stream>>>(nullptr, x2h, ln2_g, ln2_b, yb, out);
  {
    GArgs a{yb, w1t, c1b, nullptr, nullptr, nullptr, pA, pB, nullptr, nullptr, zpad, 9216, 9216};
    gemm_kernel<4><<<1296, 256, 0, stream>>>(a);
  }
  gelu_reduce_kernel<<<2304, 256, 0, stream>>>(pA, pB, c1b, f1);
  {
    GArgs a{f1, w2t, c2b, nullptr, x2h, out, nullptr, nullptr, nullptr, nullptr, zpad, 9216, 2304};
    gemm_kernel<3><<<576, 256, 0, stream>>>(a);
  }
}

// Round 16
// 354.708 us; speedup vs baseline: 1.2949x; 1.0715x over previous
//
#include <hip/hip_runtime.h>

typedef unsigned short u16;
typedef unsigned int u32;
typedef __bf16 bf16x8 __attribute__((ext_vector_type(8)));
typedef float f32x4 __attribute__((ext_vector_type(4)));

#define DEVI __device__ __forceinline__

#define BB 16
#define NN 577
#define CC 1024
#define HH 16
#define DD 64
#define BN 9232     // B*N rows
#define PIX 576     // 24*24
#define WW 24
#define CHN 256
#define VROW 584    // padded v^T row length (16B-aligned rows)
#define PSZ (9216 * 256)  // one conv1 partial (elements)

DEVI u16 f2b(float f) {
  u32 u = __builtin_bit_cast(u32, f);
  u32 r = 0x7FFFu + ((u >> 16) & 1u);
  return (u16)((u + r) >> 16);
}

DEVI float b2f(u16 h) { return __builtin_bit_cast(float, (u32)h << 16); }

DEVI bf16x8 ldfrag(const u16* p) {
  uint4 u = *(const uint4*)p;
  return __builtin_bit_cast(bf16x8, u);
}

DEVI f32x4 mfma16(bf16x8 a, bf16x8 b, f32x4 c) {
  return __builtin_amdgcn_mfma_f32_16x16x32_bf16(a, b, c, 0, 0, 0);
}

DEVI void gld_lds16(const u16* g, u16* l) {
  __builtin_amdgcn_global_load_lds((const __attribute__((address_space(1))) void*)g,
                                   (__attribute__((address_space(3))) void*)l, 16, 0, 0);
}

DEVI float gelu_tanh(float v) {
  const float x3 = v * v * v;
  const float t = __expf(1.5957691216057308f * (v + 0.044715f * x3));
  const float th = (t - 1.f) / (t + 1.f);
  return 0.5f * v * (1.f + th);
}

// ---------------- prep: weight bf16 conversion + conv-weight permute + zero page ----
__global__ __launch_bounds__(256) void prep_kernel(
    const float* __restrict__ in_w, const float* __restrict__ out_w,
    const float* __restrict__ c1w, const float* __restrict__ c2w,
    u16* __restrict__ wqkv, u16* __restrict__ wout,
    u16* __restrict__ w1t, u16* __restrict__ w2t, u16* __restrict__ zpad) {
  const int i0 = blockIdx.x * 256 + threadIdx.x;
  const int stride = gridDim.x * 256;
  for (int i = i0; i < 3072 * 1024; i += stride) wqkv[i] = f2b(in_w[i]);
  for (int i = i0; i < 1024 * 1024; i += stride) wout[i] = f2b(out_w[i]);
  for (int i = i0; i < 256 * 9216; i += stride) {
    int oc = i / 9216, rem = i - oc * 9216, tap = rem >> 10, c = rem & 1023;
    w1t[i] = f2b(c1w[(size_t)oc * 9216 + c * 9 + tap]);
  }
  for (int i = i0; i < 1024 * 2304; i += stride) {
    int oc = i / 2304, rem = i - oc * 2304, tap = rem >> 8, c = rem & 255;
    w2t[i] = f2b(c2w[(size_t)oc * 2304 + c * 9 + tap]);
  }
  if (i0 < 128) zpad[i0] = 0;
}

// ---------------- LayerNorm (row of 1024): MODE0 f32 in; MODE1 bf16 in + cls out ----
template <int MODE>
__global__ __launch_bounds__(256) void ln_kernel(
    const float* __restrict__ xf, const u16* __restrict__ xh,
    const float* __restrict__ gam, const float* __restrict__ bet,
    u16* __restrict__ yout, float* __restrict__ oextra) {
  __shared__ float sh[8];
  const int row = blockIdx.x;
  const int tid = threadIdx.x;
  float4 v;
  if constexpr (MODE == 0) {
    v = ((const float4*)(xf + (size_t)row * CC))[tid];
  } else {
    ushort4 uv = ((const ushort4*)(xh + (size_t)row * CC))[tid];
    v = make_float4(b2f(uv.x), b2f(uv.y), b2f(uv.z), b2f(uv.w));
  }
  float s = v.x + v.y + v.z + v.w;
  float qq = v.x * v.x + v.y * v.y + v.z * v.z + v.w * v.w;
#pragma unroll
  for (int off = 32; off > 0; off >>= 1) {
    s += __shfl_down(s, off);
    qq += __shfl_down(qq, off);
  }
  if ((tid & 63) == 0) { sh[tid >> 6] = s; sh[4 + (tid >> 6)] = qq; }
  __syncthreads();
  s = sh[0] + sh[1] + sh[2] + sh[3];
  qq = sh[4] + sh[5] + sh[6] + sh[7];
  const float mu = s * (1.f / 1024.f);
  const float rstd = rsqrtf(qq * (1.f / 1024.f) - mu * mu + 1e-5f);
  const float4 g4 = ((const float4*)gam)[tid];
  const float4 b4 = ((const float4*)bet)[tid];
  const float o0 = (v.x - mu) * rstd * g4.x + b4.x;
  const float o1 = (v.y - mu) * rstd * g4.y + b4.y;
  const float o2 = (v.z - mu) * rstd * g4.z + b4.z;
  const float o3 = (v.w - mu) * rstd * g4.w + b4.w;
  ushort4 st = make_ushort4(f2b(o0), f2b(o1), f2b(o2), f2b(o3));
  *(ushort4*)(yout + (size_t)row * CC + tid * 4) = st;
  if constexpr (MODE == 1) {
    if (row % NN == NN - 1) {  // cls token row: out = x2 + ln2(x2)
      float4 ov = make_float4(v.x + o0, v.y + o1, v.z + o2, v.w + o3);
      ((float4*)(oextra + (size_t)row * CC))[tid] = ov;
    }
  }
}

struct GArgs {
  const u16* A; const u16* Bm; const float* bias; const float* res; const u16* resH;
  float* outF; u16* outH; u16* outQ; u16* outK; u16* outV; const u16* zpad;
  int M, K;
};

// ================= QKV: 256x256 8-phase-style MFMA GEMM (m201 template) ==============
// 512 thr, 8 waves (2M x 4N, wave tile 128x64), BK=64, 128 KB dbuf LDS.
// m-major XCD decode: each XCD owns ~4.6 consecutive m-strips (A resident in L2).
__global__ __launch_bounds__(512, 1) void qkv_kernel(GArgs ag) {
  __shared__ u16 SH[65536];  // A: 2 x 16384 @0 ; B: 2 x 16384 @32768  (128 KB)
  const int tid = threadIdx.x;
  const int w = tid >> 6, l = tid & 63;
  const int wm = w >> 2, wn = w & 3;
  const int lr = l & 15, lg = l >> 4;
  // grid 444 = 37m x 12n; bijective XCD chunk (m204): q=55, r=4; m-major within chunk
  const int orig = blockIdx.x;
  const int xcd = orig & 7;
  const int wg = (xcd < 4 ? xcd * 56 : 224 + (xcd - 4) * 55) + (orig >> 3);
  const int mt = wg / 12, nt = wg - mt * 12;
  const int m0 = mt * 256, n0 = nt * 256;

  const int srow = tid >> 3;           // staging row within a 64-row pass
  const int schk = tid & 7;

  auto stageA = [&](int buf, int kt, int j) {
    const int row = j * 64 + srow;
    const int ch = schk ^ (row & 7);
    int m = m0 + row;
    m = m < ag.M ? m : ag.M - 1;
    gld_lds16(ag.A + (size_t)m * 1024 + kt * 64 + ch * 8,
              &SH[buf * 16384 + (j * 64 + w * 8) * 64]);
  };
  auto stageB = [&](int buf, int kt, int j) {
    const int row = j * 64 + srow;
    const int ch = schk ^ (row & 7);
    gld_lds16(ag.Bm + (size_t)(n0 + row) * 1024 + kt * 64 + ch * 8,
              &SH[32768 + buf * 16384 + (j * 64 + w * 8) * 64]);
  };

  f32x4 acc[8][4] = {};

#pragma unroll
  for (int j = 0; j < 4; ++j) { stageA(0, 0, j); stageB(0, 0, j); }

  for (int kt = 0; kt < 16; ++kt) {
    asm volatile("s_waitcnt vmcnt(0)" ::: "memory");
    __builtin_amdgcn_s_barrier();
    const int bf = kt & 1, nb = bf ^ 1;
    const u16* AB = &SH[bf * 16384];
    const u16* BBm = &SH[32768 + bf * 16384];
    bf16x8 bfr[4];
#pragma unroll
    for (int ph = 0; ph < 4; ++ph) {
      const int mg = (ph & 1) << 2;   // mi group base (0 or 4)
      const int kh = ph >> 1;         // k-half (0 or 1)
      bf16x8 af[4];
#pragma unroll
      for (int i = 0; i < 4; ++i) {
        const int ra = wm * 128 + (mg + i) * 16 + lr;
        af[i] = ldfrag(&AB[ra * 64 + (((kh << 2) + lg) ^ (ra & 7)) * 8]);
      }
      if ((ph & 1) == 0) {
#pragma unroll
        for (int i = 0; i < 4; ++i) {
          const int rb = wn * 64 + i * 16 + lr;
          bfr[i] = ldfrag(&BBm[rb * 64 + (((kh << 2) + lg) ^ (rb & 7)) * 8]);
        }
      }
      if (kt + 1 < 16) {
        stageA(nb, kt + 1, ph);
        stageB(nb, kt + 1, ph);
      }
      __builtin_amdgcn_s_barrier();
      asm volatile("s_waitcnt lgkmcnt(0)" ::: "memory");
      __builtin_amdgcn_s_setprio(1);
#pragma unroll
      for (int mi = 0; mi < 4; ++mi)
#pragma unroll
        for (int ni = 0; ni < 4; ++ni)
          acc[mg + mi][ni] = mfma16(af[mi], bfr[ni], acc[mg + mi][ni]);
      __builtin_amdgcn_s_setprio(0);
      __builtin_amdgcn_s_barrier();
    }
  }

  // ---- epilogue: row = m0 + wm*128 + mi*16 + lg*4 + r ; col = n0 + wn*64 + ni*16 + lr
  if (n0 >= 2048) {
    // v: per wave two 64x64 LDS transposes, write v^T n-contiguous
    __syncthreads();
    const int hh = (n0 + wn * 64 - 2048) >> 6;
    u16* scr = SH + w * 5120;  // 64 x 80 u16 per wave (8 waves = 80 KB)
#pragma unroll
    for (int qh = 0; qh < 2; ++qh) {
      if (qh) { asm volatile("s_waitcnt lgkmcnt(0)" ::: "memory"); }
      const int G0 = m0 + wm * 128 + qh * 64;
      const int b0q = G0 / NN;
      const bool ok = (G0 + 63 < ag.M) && (b0q == (G0 + 63) / NN);
      if (ok) {
#pragma unroll
        for (int mi = 0; mi < 4; ++mi) {
#pragma unroll
          for (int ni = 0; ni < 4; ++ni) {
            const f32x4 a4 = acc[qh * 4 + mi][ni];
            const float bv = ag.bias[n0 + wn * 64 + ni * 16 + lr];
            ushort4 st;
            st.x = f2b(a4[0] + bv);
            st.y = f2b(a4[1] + bv);
            st.z = f2b(a4[2] + bv);
            st.w = f2b(a4[3] + bv);
            *(ushort4*)(scr + (ni * 16 + lr) * 80 + mi * 16 + lg * 4) = st;
          }
        }
        asm volatile("s_waitcnt lgkmcnt(0)" ::: "memory");
        const int nb2 = G0 - b0q * NN;
        u16* vb = ag.outV + (size_t)((b0q * 16 + hh) * 64) * VROW;
#pragma unroll
        for (int pass = 0; pass < 8; ++pass) {
          const int d_ = pass * 8 + (l >> 3);
          const int nn = (l & 7) * 8;
          uint4 vv = *(const uint4*)(scr + d_ * 80 + nn);
          u16* dst = vb + (size_t)d_ * VROW + nb2 + nn;
          if (!(nb2 & 1)) {
            ((u32*)dst)[0] = vv.x; ((u32*)dst)[1] = vv.y;
            ((u32*)dst)[2] = vv.z; ((u32*)dst)[3] = vv.w;
          } else {
            u16 tmp[8];
            *(uint4*)tmp = vv;
#pragma unroll
            for (int j = 0; j < 8; ++j) dst[j] = tmp[j];
          }
        }
      } else {
#pragma unroll
        for (int mi = 0; mi < 4; ++mi) {
#pragma unroll
          for (int r = 0; r < 4; ++r) {
            const int row = G0 + mi * 16 + lg * 4 + r;
            if (row >= ag.M) continue;
            const int b = row / NN, n = row - b * NN;
#pragma unroll
            for (int ni = 0; ni < 4; ++ni) {
              const int col = n0 + wn * 64 + ni * 16 + lr;
              const int d = col & 63;
              const float v = acc[qh * 4 + mi][ni][r] + ag.bias[col];
              ag.outV[((size_t)((b * 16 + hh) * 64 + d)) * VROW + n] = f2b(v);
            }
          }
        }
      }
    }
    return;
  }
  const bool isQ = n0 < 1024;
#pragma unroll
  for (int mi = 0; mi < 8; ++mi) {
#pragma unroll
    for (int r = 0; r < 4; ++r) {
      const int row = m0 + wm * 128 + mi * 16 + (lg << 2) + r;
      if (row >= ag.M) continue;
      const int b = row / NN, n = row - b * NN;
#pragma unroll
      for (int ni = 0; ni < 4; ++ni) {
        const int col = n0 + wn * 64 + ni * 16 + lr;
        const int hd = col & 1023, h = hd >> 6, d = hd & 63;
        const float v = acc[mi][ni][r] + ag.bias[col];
        if (isQ)
          ag.outQ[((size_t)(b * 16 + h) * NN + n) * DD + d] = f2b(v * 0.18033688011112042f);
        else
          ag.outK[((size_t)(b * 16 + h) * NN + n) * DD + d] = f2b(v);
      }
    }
  }
}

// ---------------- 128x128 MFMA GEMM, BK=32, 3-buffer depth-2 pipeline (48 KB LDS) ---
// XCD-local decodes: MODE1 584 (~9 m-strips/XCD x 8n), MODE3 576 (9 m-strips/XCD x 8n),
// MODE4 1296 = 8x162 tap-major with nt-fastest inside each m-tile.
template <int MODE>
__global__ __launch_bounds__(256) void gemm_kernel(GArgs ag) {
  __shared__ u16 SH[24576];
  const int tid = threadIdx.x;
  const int w = tid >> 6, l = tid & 63;
  const int wr = w >> 1, wc = w & 1;
  const int lr = l & 15, lg = l >> 4;
  const int bid = blockIdx.x;
  int mt, nt, tapz = 0;
  if constexpr (MODE == 1) {
    const int wg = (bid & 7) * 73 + (bid >> 3);
    mt = wg >> 3; nt = wg & 7;
  } else if constexpr (MODE == 3) {
    const int idx = bid >> 3;
    mt = (bid & 7) * 9 + (idx >> 3); nt = idx & 7;
  } else {
    const int g = (bid & 7) * 162 + (bid >> 3);
    tapz = g / 144;
    const int rem = g - tapz * 144;
    mt = rem >> 1; nt = rem & 1;
  }
  const int m0 = mt * 128, n0 = nt * 128;
  const int rA = w * 16 + (l >> 2);
  const int cbs = ((l & 3) ^ ((l >> 3) & 3)) * 8;

  auto stage = [&](int buf, int kt) {
    const int k0 = kt * 32;
    u16* Ald = SH + buf * 4096;
    u16* Bld = SH + 12288 + buf * 4096;
#pragma unroll
    for (int c = 0; c < 2; ++c) {
      const int r = c * 64 + rA;
      const u16* asrc;
      if constexpr (MODE == 1) {
        int m = m0 + r;
        m = m < ag.M ? m : ag.M - 1;
        asrc = ag.A + (size_t)m * ag.K + (k0 + cbs);
      } else {
        const int m = m0 + r;
        const int b = m / PIX, p = m - b * PIX;
        const int py = p / WW, px = p - py * WW;
        constexpr int CKc = (MODE == 3) ? 256 : 1024;
        const int tap = (MODE == 4) ? tapz : (k0 / CKc);
        const int c0 = (MODE == 4) ? k0 : (k0 - tap * CKc);
        const int py2 = py + (tap / 3) - 1, px2 = px + (tap % 3) - 1;
        if ((u32)py2 < (u32)WW && (u32)px2 < (u32)WW) {
          if constexpr (MODE == 4)
            asrc = ag.A + ((size_t)(b * NN + py2 * WW + px2) * CC + c0 + cbs);
          else
            asrc = ag.A + ((size_t)(b * PIX + py2 * WW + px2) * CHN + c0 + cbs);
        } else {
          asrc = ag.zpad + cbs;
        }
      }
      gld_lds16(asrc, &Ald[c * 2048 + w * 512]);
      const u16* bsrc;
      if constexpr (MODE == 4)
        bsrc = ag.Bm + (size_t)(n0 + r) * 9216 + (tapz * 1024 + k0 + cbs);
      else
        bsrc = ag.Bm + (size_t)(n0 + r) * ag.K + (k0 + cbs);
      gld_lds16(bsrc, &Bld[c * 2048 + w * 512]);
    }
  };

  f32x4 acc[4][4] = {};
  const int KL = (MODE == 4) ? 1024 : ag.K;
  const int nst = KL >> 5;

  stage(0, 0);
  stage(1, 1);

  const int swz = (lr >> 1) & 3;
  int b0 = 0, b1 = 1, b2 = 2;
  for (int kt = 0; kt < nst; ++kt) {
    if (kt + 1 < nst) { asm volatile("s_waitcnt vmcnt(4)" ::: "memory"); }
    else              { asm volatile("s_waitcnt vmcnt(0)" ::: "memory"); }
    __builtin_amdgcn_s_barrier();
    if (kt + 2 < nst) stage(b2, kt + 2);
    bf16x8 af[4], bfr[4];
#pragma unroll
    for (int i = 0; i < 4; ++i)
      af[i] = ldfrag(&SH[b0 * 4096 + (wr * 64 + i * 16 + lr) * 32 + ((lg ^ swz) * 8)]);
#pragma unroll
    for (int i = 0; i < 4; ++i)
      bfr[i] = ldfrag(&SH[12288 + b0 * 4096 + (wc * 64 + i * 16 + lr) * 32 + ((lg ^ swz) * 8)]);
    __builtin_amdgcn_s_setprio(1);
#pragma unroll
    for (int mi = 0; mi < 4; ++mi)
#pragma unroll
      for (int ni = 0; ni < 4; ++ni) acc[mi][ni] = mfma16(af[mi], bfr[ni], acc[mi][ni]);
    __builtin_amdgcn_s_setprio(0);
    const int tmp = b0; b0 = b1; b1 = b2; b2 = tmp;
  }

#pragma unroll
  for (int mi = 0; mi < 4; ++mi) {
#pragma unroll
    for (int r = 0; r < 4; ++r) {
      const int row = m0 + wr * 64 + mi * 16 + lg * 4 + r;
      if (row >= ag.M) continue;
#pragma unroll
      for (int ni = 0; ni < 4; ++ni) {
        const int col = n0 + wc * 64 + ni * 16 + lr;
        if constexpr (MODE == 4) {
          u16* pb = (tapz < 5) ? ag.outH : ag.outQ;
          const int tl = (tapz < 5) ? tapz : tapz - 5;
          pb[(size_t)tl * PSZ + (size_t)row * CHN + col] = f2b(acc[mi][ni][r]);
        } else if constexpr (MODE == 1) {
          const size_t idx = (size_t)row * CC + col;
          ag.outH[idx] = f2b(acc[mi][ni][r] + ag.bias[col] + ag.res[idx]);
        } else {
          const int b = row / PIX, p = row - b * PIX;
          const size_t idx = (size_t)(b * NN + p) * CC + col;
          ag.outF[idx] = acc[mi][ni][r] + ag.bias[col] + b2f(ag.resH[idx]);
        }
      }
    }
  }
}

// ---------------- conv1 reduce: f1 = gelu(sum of 9 bf16 partials + bias) -> bf16 ----
__global__ __launch_bounds__(256) void gelu_reduce_kernel(
    const u16* __restrict__ pA, const u16* __restrict__ pB,
    const float* __restrict__ bias, u16* __restrict__ f1) {
  const size_t i4 = ((size_t)blockIdx.x * 256 + threadIdx.x) * 4;
  const int col = (int)(i4 & 255);
  float s0 = 0.f, s1 = 0.f, s2 = 0.f, s3 = 0.f;
#pragma unroll
  for (int t = 0; t < 5; ++t) {
    ushort4 u = *(const ushort4*)(pA + (size_t)t * PSZ + i4);
    s0 += b2f(u.x); s1 += b2f(u.y); s2 += b2f(u.z); s3 += b2f(u.w);
  }
#pragma unroll
  for (int t = 0; t < 4; ++t) {
    ushort4 u = *(const ushort4*)(pB + (size_t)t * PSZ + i4);
    s0 += b2f(u.x); s1 += b2f(u.y); s2 += b2f(u.z); s3 += b2f(u.w);
  }
  const float4 b4 = *(const float4*)(bias + col);
  ushort4 st = make_ushort4(f2b(gelu_tanh(s0 + b4.x)), f2b(gelu_tanh(s1 + b4.y)),
                            f2b(gelu_tanh(s2 + b4.z)), f2b(gelu_tanh(s3 + b4.w)));
  *(ushort4*)(f1 + i4) = st;
}

// ---------------- fused flash attention v3: 8 waves, QBLK=128, LDS-shared K/V -------
__global__ __launch_bounds__(512) void attn_kernel(
    const u16* __restrict__ q, const u16* __restrict__ k,
    const u16* __restrict__ vt, u16* __restrict__ o) {
  __shared__ u16 SH2[24576];
  const int tid = threadIdx.x;
  const int w = tid >> 6, l = tid & 63;
  const int lr = l & 15, lg = l >> 4;
  const int lg4 = lg * 4;
  const int bid = blockIdx.x;
  const int xcd = bid & 7, gg = bid >> 3;
  const int bh = (gg / 5) * 8 + xcd;
  const int qt = gg % 5;
  const int b = bh >> 4, h = bh & 15;

  const u16* qp = q + (size_t)bh * NN * DD;
  const u16* kp = k + (size_t)bh * NN * DD;
  const u16* vp = vt + (size_t)bh * DD * VROW;

  const int qrow = qt * 128 + w * 16 + lr;
  const int qrc = qrow < NN ? qrow : NN - 1;
  const bf16x8 qf0 = ldfrag(qp + (size_t)qrc * DD + lg * 8);
  const bf16x8 qf1 = ldfrag(qp + (size_t)qrc * DD + 32 + lg * 8);

  const int srow = l >> 3;
  const int schk = (l & 7) ^ (srow & 7);
  auto stage = [&](int buf, int kt) {
    const int kb = kt * 64;
    gld_lds16(kp + (size_t)(kb + w * 8 + srow) * DD + schk * 8,
              &SH2[buf * 4096 + w * 512]);
    gld_lds16(vp + (size_t)(w * 8 + srow) * VROW + kb + schk * 8,
              &SH2[8192 + buf * 4096 + w * 512]);
  };

  f32x4 oa[4] = {};
  float mrow = -1e30f;
  float lsum = 0.f;
  u16* pw = &SH2[16384 + w * 1024];
  const int x7 = lr & 7;
  const int x3 = lr & 3;

  stage(0, 0);
  stage(1, 1);

  for (int kt = 0; kt < 10; ++kt) {
    if (kt <= 7) { asm volatile("s_waitcnt vmcnt(2)" ::: "memory"); }
    else         { asm volatile("s_waitcnt vmcnt(0)" ::: "memory"); }
    __builtin_amdgcn_s_barrier();
    const u16* KB = &SH2[(kt & 1) * 4096];
    const u16* VB = &SH2[8192 + (kt & 1) * 4096];
    const int kb = kt * 64;

    f32x4 s[4] = {};
#pragma unroll
    for (int g = 0; g < 4; ++g) {
      const int row = g * 16 + lr;
      const bf16x8 a0 = ldfrag(&KB[row * 64 + ((lg ^ x7) * 8)]);
      const bf16x8 a1 = ldfrag(&KB[row * 64 + (((4 + lg) ^ x7) * 8)]);
      s[g] = mfma16(a0, qf0, s[g]);
      s[g] = mfma16(a1, qf1, s[g]);
    }
    float t[16];
    const bool last = (kt == 9);
#pragma unroll
    for (int g = 0; g < 4; ++g)
#pragma unroll
      for (int r = 0; r < 4; ++r) {
        const int key = kb + g * 16 + lg4 + r;
        t[g * 4 + r] = (!last || key < NN) ? s[g][r] : -3e38f;
      }
    float pmax = t[0];
#pragma unroll
    for (int i = 1; i < 16; ++i) pmax = fmaxf(pmax, t[i]);
    pmax = fmaxf(pmax, __shfl_xor(pmax, 16));
    pmax = fmaxf(pmax, __shfl_xor(pmax, 32));
    if (!__all(pmax <= mrow + 8.f)) {
      const float mn = fmaxf(mrow, pmax);
      const float corr = exp2f(mrow - mn);
      mrow = mn;
      lsum *= corr;
      float bc[4];
#pragma unroll
      for (int r = 0; r < 4; ++r) bc[r] = __shfl(corr, (l & 48) | (lg4 + r));
#pragma unroll
      for (int g = 0; g < 4; ++g)
#pragma unroll
        for (int r = 0; r < 4; ++r) oa[g][r] *= bc[r];
    }
    float ps[16];
    float rsum = 0.f;
#pragma unroll
    for (int i = 0; i < 16; ++i) { ps[i] = exp2f(t[i] - mrow); rsum += ps[i]; }
    rsum += __shfl_xor(rsum, 16);
    rsum += __shfl_xor(rsum, 32);
    lsum += rsum;
#pragma unroll
    for (int g = 0; g < 4; ++g) {
      u32 w0, w1;
      asm("v_cvt_pk_bf16_f32 %0, %1, %2" : "=v"(w0) : "v"(ps[g * 4 + 0]), "v"(ps[g * 4 + 1]));
      asm("v_cvt_pk_bf16_f32 %0, %1, %2" : "=v"(w1) : "v"(ps[g * 4 + 2]), "v"(ps[g * 4 + 3]));
      const int lc = (g & 1) * 2 + (lg >> 1);
      const int off = (g >> 1) * 512 + lr * 32 + ((lc ^ x3) * 8) + (lg & 1) * 4;
      *(uint2*)(&pw[off]) = make_uint2(w0, w1);
    }
    asm volatile("s_waitcnt lgkmcnt(0)" ::: "memory");
    const bf16x8 paf = ldfrag(&pw[lr * 32 + ((lg ^ x3) * 8)]);
    const bf16x8 pbf = ldfrag(&pw[512 + lr * 32 + ((lg ^ x3) * 8)]);
#pragma unroll
    for (int dg = 0; dg < 4; ++dg) {
      const int row = dg * 16 + lr;
      const bf16x8 v0 = ldfrag(&VB[row * 64 + ((lg ^ x7) * 8)]);
      const bf16x8 v1 = ldfrag(&VB[row * 64 + (((4 + lg) ^ x7) * 8)]);
      oa[dg] = mfma16(paf, v0, oa[dg]);
      oa[dg] = mfma16(pbf, v1, oa[dg]);
    }
    asm volatile("s_waitcnt lgkmcnt(0)" ::: "memory");
    __builtin_amdgcn_s_barrier();
    if (kt + 2 <= 9) stage(kt & 1, kt + 2);
  }

  const int nq = qt * 128 + w * 16 + lg4;
  float linv[4];
#pragma unroll
  for (int r = 0; r < 4; ++r) linv[r] = __shfl(lsum, (l & 48) | (lg4 + r));
#pragma unroll
  for (int r = 0; r < 4; ++r) {
    const int n = nq + r;
    if (n >= NN) continue;
    const float inv = 1.0f / linv[r];
#pragma unroll
    for (int g = 0; g < 4; ++g)
      o[(size_t)(b * NN + n) * CC + h * DD + g * 16 + lr] = f2b(oa[g][r] * inv);
  }
}

// =====================================================================================
extern "C" void kernel_launch(void* const* d_in, const int* in_sizes, int n_in,
                              void* d_out, int out_size, void* d_ws, size_t ws_size,
                              hipStream_t stream) {
  const float* x     = (const float*)d_in[0];
  const float* ln1_g = (const float*)d_in[1];
  const float* ln1_b = (const float*)d_in[2];
  const float* in_w  = (const float*)d_in[3];
  const float* in_b  = (const float*)d_in[4];
  const float* out_w = (const float*)d_in[5];
  const float* out_b = (const float*)d_in[6];
  const float* ln2_g = (const float*)d_in[7];
  const float* ln2_b = (const float*)d_in[8];
  const float* c1w   = (const float*)d_in[9];
  const float* c1b   = (const float*)d_in[10];
  const float* c2w   = (const float*)d_in[11];
  const float* c2b   = (const float*)d_in[12];
  float* out = (float*)d_out;

  char* ws = (char*)d_ws;
  size_t off = 0;
  auto alloc = [&](size_t bytes) {
    void* p = ws + off;
    off += (bytes + 255) & ~(size_t)255;
    return p;
  };
  u16* hb   = (u16*)alloc((size_t)BN * CC * 2);
  u16* wqkv = (u16*)alloc((size_t)3072 * 1024 * 2);
  u16* wout = (u16*)alloc((size_t)1024 * 1024 * 2);
  u16* w1t  = (u16*)alloc((size_t)256 * 9216 * 2);
  u16* w2t  = (u16*)alloc((size_t)1024 * 2304 * 2);
  u16* qb   = (u16*)alloc((size_t)256 * NN * DD * 2);
  u16* kb   = (u16*)alloc((size_t)256 * NN * DD * 2);
  u16* vtb  = (u16*)alloc((size_t)256 * DD * VROW * 2 + 16384);
  u16* x2h  = (u16*)alloc((size_t)BN * CC * 2);
  u16* zpad = (u16*)alloc(256);
  u16* ob = hb;
  u16* yb = qb;
  u16* f1 = kb;
  u16* pA = hb;
  u16* pB = vtb;

  prep_kernel<<<1024, 256, 0, stream>>>(in_w, out_w, c1w, c2w, wqkv, wout, w1t, w2t, zpad);
  ln_kernel<0><<<BN, 256, 0, stream>>>(x, nullptr, ln1_g, ln1_b, hb, nullptr);
  {
    GArgs a{hb, wqkv, in_b, nullptr, nullptr, nullptr, nullptr, qb, kb, vtb, zpad, BN, CC};
    qkv_kernel<<<444, 512, 0, stream>>>(a);
  }
  attn_kernel<<<1280, 512, 0, stream>>>(qb, kb, vtb, ob);
  {
    GArgs a{ob, wout, out_b, x, nullptr, nullptr, x2h, nullptr, nullptr, nullptr, zpad, BN, CC};
    gemm_kernel<1><<<584, 256, 0, stream>>>(a);
  }
  ln_kernel<1><<<BN, 256, 0, stream>>>(nullptr, x2h, ln2_g, ln2_b, yb, out);
  {
    GArgs a{yb, w1t, c1b, nullptr, nullptr, nullptr, pA, pB, nullptr, nullptr, zpad, 9216, 9216};
    gemm_kernel<4><<<1296, 256, 0, stream>>>(a);
  }
  gelu_reduce_kernel<<<2304, 256, 0, stream>>>(pA, pB, c1b, f1);
  {
    GArgs a{f1, w2t, c2b, nullptr, x2h, out, nullptr, nullptr, nullptr, nullptr, zpad, 9216, 2304};
    gemm_kernel<3><<<576, 256, 0, stream>>>(a);
  }
}